// Round 1
// 644.817 us; speedup vs baseline: 1.2271x; 1.2271x over previous
//
#include <hip/hip_runtime.h>
#include <math.h>

#define HDIM 128
#define NGAUSS 50
#define NLAYER 6
#define TSTR 136   // LDS bf16 tile row stride (shorts); %8==0 keeps ds_read_b128 aligned
#define DINV (1.0f/512.0f)
#define NXCD 8
#define NSTRIPE 512   // edge stripes for the deterministic CSR build

typedef unsigned short ushortT;
typedef __attribute__((ext_vector_type(8))) short bf16x8;
typedef __attribute__((ext_vector_type(4))) float f32x4;

static __device__ __forceinline__ float bf2f(unsigned short u){
  union { unsigned int i; float f; } x; x.i = ((unsigned int)u) << 16; return x.f;
}
static __device__ __forceinline__ unsigned short f2bf(float f){
  union { float f; unsigned int i; } x; x.f = f;
  unsigned int i = x.i;
  unsigned int r = (i + 0x7FFFu + ((i >> 16) & 1u)) >> 16;
  return (unsigned short)r;
}
static __device__ __forceinline__ float ssp(float x){
  return fmaxf(x, 0.0f) + __logf(1.0f + __expf(-fabsf(x))) - 0.69314718055994530942f;
}
static __device__ __forceinline__ f32x4 mfma4r(const bf16x8* a, const bf16x8* b){
  f32x4 d = {0.f, 0.f, 0.f, 0.f};
  d = __builtin_amdgcn_mfma_f32_16x16x32_bf16(a[0], b[0], d, 0, 0, 0);
  d = __builtin_amdgcn_mfma_f32_16x16x32_bf16(a[1], b[1], d, 0, 0, 0);
  d = __builtin_amdgcn_mfma_f32_16x16x32_bf16(a[2], b[2], d, 0, 0, 0);
  d = __builtin_amdgcn_mfma_f32_16x16x32_bf16(a[3], b[3], d, 0, 0, 0);
  return d;
}

// ======================= deterministic CSR build =======================
// Replaces {counts atomicAdd, scan, atomic fill}. Zero global atomics:
// stripe histograms -> column scans -> stripe-private contiguous scatter
// into row-bucket regions -> per-bucket regroup with LDS counters.

// phase 1: per-stripe histogram over row buckets (bucket = r >> shift)
__global__ __launch_bounds__(256)
void k_hist(const int* __restrict__ erow, int* __restrict__ hist,
            int E, int NB, int shift, int estripe){
  __shared__ int lh[512];
  int tid = threadIdx.x, w = blockIdx.x;
  for (int i = tid; i < NB; i += 256) lh[i] = 0;
  __syncthreads();
  int beg = w * estripe;
  int end = beg + estripe; if (end > E) end = E;
  for (int e = beg + tid; e < end; e += 256)
    atomicAdd(&lh[erow[e] >> shift], 1);
  __syncthreads();
  for (int i = tid; i < NB; i += 256) hist[w * 512 + i] = lh[i];
}

// phase 2a: per-bucket exclusive prefix over the 512 stripes (in place),
// emit per-bucket totals.
__global__ __launch_bounds__(256)
void k_colscan(int* __restrict__ hist, int* __restrict__ colTotal, int NB){
  __shared__ int sA[512], sB[512];
  int b = blockIdx.x, tid = threadIdx.x;
  sA[tid]       = hist[tid * 512 + b];
  sA[tid + 256] = hist[(tid + 256) * 512 + b];
  __syncthreads();
  int* pa = sA; int* pb = sB;
  for (int off = 1; off < 512; off <<= 1){
    for (int i = tid; i < 512; i += 256)
      pb[i] = pa[i] + (i >= off ? pa[i - off] : 0);
    __syncthreads();
    int* t = pa; pa = pb; pb = t;
  }
  int e0 = (tid == 0) ? 0 : pa[tid - 1];
  int e1 = pa[tid + 255];
  hist[tid * 512 + b]       = e0;
  hist[(tid + 256) * 512 + b] = e1;
  if (tid == 0) colTotal[b] = pa[511];
}

// phase 2b: exclusive scan over bucket totals -> bucket base (+ total at [NB])
__global__ __launch_bounds__(256)
void k_bscan(const int* __restrict__ colTotal, int* __restrict__ bucketBase, int NB){
  __shared__ int sA[512], sB[512];
  int tid = threadIdx.x;
  for (int i = tid; i < 512; i += 256) sA[i] = (i < NB) ? colTotal[i] : 0;
  __syncthreads();
  int* pa = sA; int* pb = sB;
  for (int off = 1; off < 512; off <<= 1){
    for (int i = tid; i < 512; i += 256)
      pb[i] = pa[i] + (i >= off ? pa[i - off] : 0);
    __syncthreads();
    int* t = pa; pa = pb; pb = t;
  }
  for (int i = tid; i < NB; i += 256)
    bucketBase[i] = (i == 0) ? 0 : pa[i - 1];
  if (tid == 0) bucketBase[NB] = pa[NB - 1];
}

// phase 3: scatter edges into bucket-grouped staging. Each stripe owns a
// precomputed contiguous run inside every bucket region (LDS cursors only),
// so writes fill lines back-to-back and merge in L2.
__global__ __launch_bounds__(256)
void k_scatter(const int* __restrict__ erow, const int* __restrict__ ecol,
               const float* __restrict__ pos, const int* __restrict__ hist,
               const int* __restrict__ bucketBase, uint2* __restrict__ stg,
               int E, int NB, int shift, int estripe){
  __shared__ int cur[512];
  int tid = threadIdx.x, w = blockIdx.x;
  for (int b = tid; b < NB; b += 256)
    cur[b] = bucketBase[b] + hist[w * 512 + b];
  __syncthreads();
  int beg = w * estripe;
  int end = beg + estripe; if (end > E) end = E;
  int mask = (1 << shift) - 1;
  for (int e = beg + tid; e < end; e += 256){
    int r = erow[e], c = ecol[e];
    float dx = pos[r*3+0] - pos[c*3+0];
    float dy = pos[r*3+1] - pos[c*3+1];
    float dz = pos[r*3+2] - pos[c*3+2];
    float d = sqrtf(dx*dx + dy*dy + dz*dz);
    int du = (int)(d * 512.0f + 0.5f);
    if (du > 65535) du = 65535;
    int p = atomicAdd(&cur[r >> shift], 1);   // LDS atomic
    uint2 t;
    t.x = ((unsigned int)c << 16) | (unsigned int)du;
    t.y = (unsigned int)(r & mask);
    stg[p] = t;
  }
}

// phase 4: one WG per bucket. Regroup the bucket's records by row (LDS
// histogram + scan + LDS cursors), write final csr into the bucket's own
// contiguous region, and emit offsets[] directly (replaces global scans).
__global__ __launch_bounds__(256)
void k_place(const uint2* __restrict__ stg, const int* __restrict__ bucketBase,
             int* __restrict__ offsets, unsigned int* __restrict__ csr,
             int N, int NB, int shift, int E){
  __shared__ int rc[1024];
  __shared__ int sA[1024], sB[1024];
  int b = blockIdx.x, tid = threadIdx.x;
  int R = 1 << shift;            // rows per bucket (<=1024 for N<=512K)
  int r0 = b << shift;
  int s = bucketBase[b], e2 = bucketBase[b + 1];
  for (int i = tid; i < R; i += 256) rc[i] = 0;
  __syncthreads();
  for (int j = s + tid; j < e2; j += 256)
    atomicAdd(&rc[stg[j].y], 1);
  __syncthreads();
  for (int i = tid; i < R; i += 256) sA[i] = rc[i];
  __syncthreads();
  int* pa = sA; int* pb = sB;
  for (int off = 1; off < R; off <<= 1){
    for (int i = tid; i < R; i += 256)
      pb[i] = pa[i] + (i >= off ? pa[i - off] : 0);
    __syncthreads();
    int* t = pa; pa = pb; pb = t;
  }
  for (int i = tid; i < R; i += 256){
    int excl = (i == 0) ? 0 : pa[i - 1];
    rc[i] = excl;                 // becomes the per-row cursor
    int r = r0 + i;
    if (r < N) offsets[r] = s + excl;
  }
  if (b == NB - 1 && tid == 0) offsets[N] = E;
  __syncthreads();
  for (int j = s + tid; j < e2; j += 256){
    uint2 t = stg[j];
    int slot = s + atomicAdd(&rc[t.y], 1);   // LDS atomic
    csr[slot] = t.x;                          // contiguous per-WG region
  }
}

// ---------------- merged setup (counts pass removed) ----------------
__global__ void k_setup(const int* __restrict__ z, const float* __restrict__ emb,
                        ushortT* __restrict__ vhi,
                        const float* __restrict__ Wn, ushortT* __restrict__ WnT,
                        const float* __restrict__ Wo, ushortT* __restrict__ WoT,
                        const float* __restrict__ dW, const float* __restrict__ db,
                        const float* __restrict__ We, const float* __restrict__ be,
                        float* __restrict__ a, float* __restrict__ c,
                        const int* __restrict__ batch, int* __restrict__ groupOff,
                        int N, int G, int B1, int B2, int B4, int B5){
  int b = blockIdx.x;
  int tid = threadIdx.x;
  if (b < B1){
    int idx = b * 256 + tid;
    if (idx < N * HDIM){
      int n = idx >> 7, f = idx & 127;
      vhi[idx] = f2bf(emb[z[n] * HDIM + f]);
    }
    return;
  }
  b -= B1;
  if (b < B2){
    int idx = b * 256 + tid;
    if (idx < NLAYER * HDIM * HDIM){
      int mat = idx >> 14, rem = idx & 16383;
      int n = rem >> 7, k = rem & 127;
      WnT[idx] = f2bf(Wn[(mat << 14) + k * HDIM + n]);
    }
    return;
  }
  b -= B2;
  if (b < B2){
    int idx = b * 256 + tid;
    if (idx < NLAYER * HDIM * HDIM){
      int mat = idx >> 14, rem = idx & 16383;
      int n = rem >> 7, k = rem & 127;
      WoT[idx] = f2bf(Wo[(mat << 14) + k * HDIM + n]);
    }
    return;
  }
  b -= B2;
  if (b < B4){
    int idx = b * 256 + tid;
    if (idx < NLAYER * HDIM){
      int l = idx >> 7, f = idx & 127;
      float av = 0.f, cv = 0.f;
      for (int g = 0; g < NGAUSS; ++g){
        float we = We[(l * NGAUSS + g) * HDIM + f];
        av += dW[g] * we;
        cv += db[g] * we;
      }
      a[idx] = av;
      c[idx] = cv + be[idx];
    }
    return;
  }
  b -= B4;
  if (b < B5){
    int i = b * 256 + tid;
    if (i >= N) return;
    int bb = batch[i];
    if (i == 0){
      for (int g = 0; g <= bb; ++g) groupOff[g] = 0;
    } else {
      int pb = batch[i - 1];
      for (int g = pb + 1; g <= bb; ++g) groupOff[g] = i;
    }
    if (i == N - 1){
      for (int g = bb + 1; g <= G; ++g) groupOff[g] = N;
    }
  }
}

// ---------------- initial GEMM: h0 = v0 @ Wn[0]; 2 row-tiles per wave ----------
__global__ __launch_bounds__(128, 2)
void k_gemm0(const ushortT* __restrict__ X, const ushortT* __restrict__ WT,
             ushortT* __restrict__ outHi, int N){
  int tid = threadIdx.x;
  int wave = tid >> 6, lane = tid & 63;
  int m = lane & 15, quad = lane >> 4;
  int ntiles = (N + 15) >> 4;
  int t0 = (blockIdx.x * 2 + wave) * 2;
  if (t0 >= ntiles) return;

  bf16x8 av[2][4];
  #pragma unroll
  for (int rt = 0; rt < 2; ++rt){
    int row = (t0 + rt) * 16 + m; if (row >= N) row = N - 1;
    #pragma unroll
    for (int kk = 0; kk < 4; ++kk)
      av[rt][kk] = *(const bf16x8*)(X + ((size_t)row << 7) + kk*32 + quad*8);
  }
  #pragma unroll
  for (int ct = 0; ct < 8; ++ct){
    int ncol = ct * 16 + m;
    const ushortT* bp = WT + ((size_t)ncol << 7) + quad*8;
    bf16x8 bb[4];
    #pragma unroll
    for (int kk = 0; kk < 4; ++kk) bb[kk] = *(const bf16x8*)(bp + kk*32);
    #pragma unroll
    for (int rt = 0; rt < 2; ++rt){
      f32x4 d = mfma4r(av[rt], bb);
      #pragma unroll
      for (int r = 0; r < 4; ++r){
        int orow = (t0 + rt) * 16 + quad*4 + r;
        if (orow < N) outHi[((size_t)orow << 7) + ncol] = f2bf(d[r]);
      }
    }
  }
}

// ---------------- edge aggregation, XCD-swizzled node ownership ----------------
__global__ __launch_bounds__(256, 8)
void k_agg2(const ushortT* __restrict__ h, const int* __restrict__ offsets,
            const unsigned int* __restrict__ cd, const float* __restrict__ a,
            const float* __restrict__ c, ushortT* __restrict__ aggHi,
            int N, int segNodes){
  int xcd = blockIdx.x & (NXCD - 1);
  int idx = blockIdx.x >> 3;
  int node = xcd * segNodes + idx * 4 + (threadIdx.x >> 6);
  if (node >= N || node >= (xcd + 1) * segNodes) return;
  int lane = threadIdx.x & 63;
  int half = lane >> 5;
  int fl = (lane & 31) * 4;
  float4 av = *(const float4*)(a + fl);
  float4 cv = *(const float4*)(c + fl);
  int s = offsets[node], e = offsets[node + 1];
  float acc0 = 0.f, acc1 = 0.f, acc2 = 0.f, acc3 = 0.f;
  int j = s;
  for (; j + 8 <= e; j += 8){
    unsigned int q[4]; uint2 p[4];
    #pragma unroll
    for (int i = 0; i < 4; ++i) q[i] = cd[j + 2*i + half];
    #pragma unroll
    for (int i = 0; i < 4; ++i)
      p[i] = *(const uint2*)(h + ((size_t)(q[i] >> 16) << 7) + fl);
    #pragma unroll
    for (int i = 0; i < 4; ++i){
      float dd = (float)(q[i] & 0xFFFFu) * DINV;
      acc0 = fmaf(bf2f((ushortT)p[i].x),         fmaf(dd, av.x, cv.x), acc0);
      acc1 = fmaf(bf2f((ushortT)(p[i].x >> 16)), fmaf(dd, av.y, cv.y), acc1);
      acc2 = fmaf(bf2f((ushortT)p[i].y),         fmaf(dd, av.z, cv.z), acc2);
      acc3 = fmaf(bf2f((ushortT)(p[i].y >> 16)), fmaf(dd, av.w, cv.w), acc3);
    }
  }
  for (; j < e; j += 2){
    int myj = j + half;
    if (myj < e){
      unsigned int q = cd[myj];
      uint2 p = *(const uint2*)(h + ((size_t)(q >> 16) << 7) + fl);
      float dd = (float)(q & 0xFFFFu) * DINV;
      acc0 = fmaf(bf2f((ushortT)p.x),         fmaf(dd, av.x, cv.x), acc0);
      acc1 = fmaf(bf2f((ushortT)(p.x >> 16)), fmaf(dd, av.y, cv.y), acc1);
      acc2 = fmaf(bf2f((ushortT)p.y),         fmaf(dd, av.z, cv.z), acc2);
      acc3 = fmaf(bf2f((ushortT)(p.y >> 16)), fmaf(dd, av.w, cv.w), acc3);
    }
  }
  acc0 += __shfl_down(acc0, 32, 64);
  acc1 += __shfl_down(acc1, 32, 64);
  acc2 += __shfl_down(acc2, 32, 64);
  acc3 += __shfl_down(acc3, 32, 64);
  if (half == 0){
    uint2 ph;
    ph.x = (unsigned int)f2bf(acc0) | ((unsigned int)f2bf(acc1) << 16);
    ph.y = (unsigned int)f2bf(acc2) | ((unsigned int)f2bf(acc3) << 16);
    *(uint2*)(aggHi + ((size_t)node << 7) + fl) = ph;
  }
}

// ---------------- fused GEMM pair, wave-private LDS, no barrier ----------------
__global__ __launch_bounds__(128, 2)
void k_fpair(const ushortT* __restrict__ agg, const ushortT* __restrict__ WoT,
             const float* __restrict__ bo, const ushortT* __restrict__ WnT,
             ushortT* __restrict__ outH, int N, int segTiles){
  __shared__ ushortT vt[2][32 * TSTR];
  int tid = threadIdx.x;
  int wave = tid >> 6, lane = tid & 63;
  int m = lane & 15, quad = lane >> 4;
  int ntiles = (N + 15) >> 4;
  int xcd = blockIdx.x & (NXCD - 1);
  int idx = blockIdx.x >> 3;
  int wjIdx = idx * 2 + wave;
  int segWJ = segTiles >> 1;
  if (wjIdx >= segWJ) return;
  int t0 = xcd * segTiles + wjIdx * 2;
  if (t0 >= ntiles) return;
  ushortT* vw = vt[wave];

  bf16x8 av[2][4];
  #pragma unroll
  for (int rt = 0; rt < 2; ++rt){
    int row = (t0 + rt) * 16 + m; if (row >= N) row = N - 1;
    #pragma unroll
    for (int kk = 0; kk < 4; ++kk)
      av[rt][kk] = *(const bf16x8*)(agg + ((size_t)row << 7) + kk*32 + quad*8);
  }
  #pragma unroll
  for (int ct = 0; ct < 8; ++ct){
    int ncol = ct * 16 + m;
    const ushortT* bp = WoT + ((size_t)ncol << 7) + quad*8;
    bf16x8 bb[4];
    #pragma unroll
    for (int kk = 0; kk < 4; ++kk) bb[kk] = *(const bf16x8*)(bp + kk*32);
    float bbias = bo[ncol];
    #pragma unroll
    for (int rt = 0; rt < 2; ++rt){
      f32x4 d = mfma4r(av[rt], bb);
      #pragma unroll
      for (int r = 0; r < 4; ++r)
        vw[(rt*16 + quad*4 + r) * TSTR + ncol] = f2bf(ssp(d[r] + bbias));
    }
  }
  bf16x8 a2[2][4];
  #pragma unroll
  for (int rt = 0; rt < 2; ++rt){
    #pragma unroll
    for (int kk = 0; kk < 4; ++kk)
      a2[rt][kk] = *(const bf16x8*)(&vw[(rt*16 + m) * TSTR + kk*32 + quad*8]);
  }
  #pragma unroll
  for (int ct = 0; ct < 8; ++ct){
    int ncol = ct * 16 + m;
    const ushortT* bp = WnT + ((size_t)ncol << 7) + quad*8;
    bf16x8 bb[4];
    #pragma unroll
    for (int kk = 0; kk < 4; ++kk) bb[kk] = *(const bf16x8*)(bp + kk*32);
    #pragma unroll
    for (int rt = 0; rt < 2; ++rt){
      f32x4 d = mfma4r(a2[rt], bb);
      #pragma unroll
      for (int r = 0; r < 4; ++r){
        int orow = (t0 + rt) * 16 + quad*4 + r;
        if (orow < N) outH[((size_t)orow << 7) + ncol] = f2bf(d[r]);
      }
    }
  }
}

// ---------------- last-layer GEMM 1: v = ssp(agg @ Wo + bo) -> vb (bf16) ------
__global__ __launch_bounds__(128, 2)
void k_g1(const ushortT* __restrict__ agg, const ushortT* __restrict__ WoT,
          const float* __restrict__ bo, ushortT* __restrict__ vb,
          int N, int segTiles){
  int tid = threadIdx.x;
  int wave = tid >> 6, lane = tid & 63;
  int m = lane & 15, quad = lane >> 4;
  int ntiles = (N + 15) >> 4;
  int xcd = blockIdx.x & (NXCD - 1);
  int idx = blockIdx.x >> 3;
  int wjIdx = idx * 2 + wave;
  int segWJ = segTiles >> 1;
  if (wjIdx >= segWJ) return;
  int t0 = xcd * segTiles + wjIdx * 2;
  if (t0 >= ntiles) return;

  bf16x8 av[2][4];
  #pragma unroll
  for (int rt = 0; rt < 2; ++rt){
    int row = (t0 + rt) * 16 + m; if (row >= N) row = N - 1;
    #pragma unroll
    for (int kk = 0; kk < 4; ++kk)
      av[rt][kk] = *(const bf16x8*)(agg + ((size_t)row << 7) + kk*32 + quad*8);
  }
  #pragma unroll
  for (int ct = 0; ct < 8; ++ct){
    int ncol = ct * 16 + m;
    const ushortT* bp = WoT + ((size_t)ncol << 7) + quad*8;
    bf16x8 bb[4];
    #pragma unroll
    for (int kk = 0; kk < 4; ++kk) bb[kk] = *(const bf16x8*)(bp + kk*32);
    float bbias = bo[ncol];
    #pragma unroll
    for (int rt = 0; rt < 2; ++rt){
      f32x4 d = mfma4r(av[rt], bb);
      #pragma unroll
      for (int r = 0; r < 4; ++r){
        int orow = (t0 + rt) * 16 + quad*4 + r;
        if (orow < N) vb[((size_t)orow << 7) + ncol] = f2bf(ssp(d[r] + bbias));
      }
    }
  }
}

// ---------------- readout from vb: one wave per node ----------------
__global__ __launch_bounds__(256, 8)
void k_read(const ushortT* __restrict__ vb,
            const float* __restrict__ W1, const float* __restrict__ b1,
            const float* __restrict__ W2, const float* __restrict__ b2,
            float* __restrict__ u, int N, int segNodes){
  __shared__ float vbuf[4][HDIM];
  int xcd = blockIdx.x & (NXCD - 1);
  int idx = blockIdx.x >> 3;
  int wave = threadIdx.x >> 6, lane = threadIdx.x & 63;
  int node = xcd * segNodes + idx * 4 + wave;
  if (node >= N || node >= (xcd + 1) * segNodes) return;
  int f = lane * 2;
  unsigned int hh = *(const unsigned int*)(vb + ((size_t)node << 7) + f);
  vbuf[wave][f]     = bf2f((ushortT)hh);
  vbuf[wave][f + 1] = bf2f((ushortT)(hh >> 16));
  float t0 = b1[lane], t1 = 0.f;
  #pragma unroll 8
  for (int k = 0; k < HDIM; k += 2){
    t0 = fmaf(vbuf[wave][k],     W1[k * 64 + lane],       t0);
    t1 = fmaf(vbuf[wave][k + 1], W1[(k + 1) * 64 + lane], t1);
  }
  float partial = ssp(t0 + t1) * W2[lane];
  #pragma unroll
  for (int off = 32; off > 0; off >>= 1)
    partial += __shfl_down(partial, off, 64);
  if (lane == 0) u[node] = partial + b2[0];
}

// ---------------- group segment sum over sorted batch ----------------
__global__ void k_gsum(const float* __restrict__ u, const int* __restrict__ groupOff,
                       float* __restrict__ out, int G){
  int g = blockIdx.x * 4 + (threadIdx.x >> 6);
  if (g >= G) return;
  int lane = threadIdx.x & 63;
  int s = groupOff[g], e = groupOff[g + 1];
  float acc = 0.f;
  for (int j = s + lane; j < e; j += 64) acc += u[j];
  #pragma unroll
  for (int off = 32; off > 0; off >>= 1)
    acc += __shfl_down(acc, off, 64);
  if (lane == 0) out[g] = acc;
}

extern "C" void kernel_launch(void* const* d_in, const int* in_sizes, int n_in,
                              void* d_out, int out_size, void* d_ws, size_t ws_size,
                              hipStream_t stream){
  const int N = in_sizes[0];
  const int E = in_sizes[3] / 2;
  const int G = out_size;

  const int*   z     = (const int*)d_in[0];
  const float* pos   = (const float*)d_in[1];
  const int*   batch = (const int*)d_in[2];
  const int*   eidx  = (const int*)d_in[3];
  const int*   erow  = eidx;
  const int*   ecol  = eidx + E;
  const float* emb   = (const float*)d_in[4];
  const float* dW    = (const float*)d_in[5];
  const float* db    = (const float*)d_in[6];
  const float* Wn    = (const float*)d_in[7];
  const float* We    = (const float*)d_in[8];
  const float* be    = (const float*)d_in[9];
  const float* Wo    = (const float*)d_in[10];
  const float* bo    = (const float*)d_in[11];
  const float* W1    = (const float*)d_in[12];
  const float* b1    = (const float*)d_in[13];
  const float* W2    = (const float*)d_in[14];
  const float* b2    = (const float*)d_in[15];

  char* ws = (char*)d_ws;
  size_t off = 0;
  auto alloc = [&](size_t bytes) -> char* {
    char* p = ws + off;
    off = (off + bytes + 255) & ~(size_t)255;
    return p;
  };
  size_t hbytes = (size_t)N * HDIM * 2;
  size_t stgbytes = (size_t)E * 8;
  int*          offsets  = (int*)         alloc((size_t)(N + 1) * 4);
  unsigned int* csr      = (unsigned int*)alloc((size_t)E * 4);
  ushortT*      h0       = (ushortT*)     alloc(hbytes);
  ushortT*      h1       = (ushortT*)     alloc(hbytes);    // aliased by hist during build
  ushortT*      vhi      = (ushortT*)     alloc(hbytes);
  ushortT*      agghi    = (ushortT*)     alloc(hbytes);
  ushortT*      vb       = (ushortT*)     alloc(hbytes > stgbytes ? hbytes : stgbytes); // aliased by stg
  ushortT*      WnT      = (ushortT*)     alloc((size_t)NLAYER * HDIM * HDIM * 2);
  ushortT*      WoT      = (ushortT*)     alloc((size_t)NLAYER * HDIM * HDIM * 2);
  float*        a        = (float*)       alloc((size_t)NLAYER * HDIM * 4);
  float*        c        = (float*)       alloc((size_t)NLAYER * HDIM * 4);
  float*        u        = (float*)       alloc((size_t)N * 4);
  int*          groupOff = (int*)         alloc((size_t)(G + 1) * 4);

  // CSR-build scratch aliases buffers that are only live later:
  // hist/colTotal/bucketBase in h1 (first written by layer-0 k_fpair),
  // staging records in vb (first written by last-layer k_g1).
  int*   hist       = (int*)h1;                 // NSTRIPE*512 ints = 1 MB
  int*   colTotal   = hist + NSTRIPE * 512;     // 512 ints
  int*   bucketBase = colTotal + 512;           // NB+1 ints
  uint2* stg        = (uint2*)vb;               // E * 8 B

  // bucket geometry: smallest shift with <=512 buckets (shift=7 for N=50000)
  int shift = 7;
  while ((((N - 1) >> shift) + 1) > 512) ++shift;
  int NB = ((N - 1) >> shift) + 1;
  int estripe = (E + NSTRIPE - 1) / NSTRIPE;

  int B1 = (N * HDIM + 255) / 256;
  int B2 = (NLAYER * HDIM * HDIM + 255) / 256;
  int B4 = (NLAYER * HDIM + 255) / 256;
  int B5 = (N + 255) / 256;
  k_setup<<<B1 + 2*B2 + B4 + B5, 256, 0, stream>>>(
      z, emb, vhi, Wn, WnT, Wo, WoT,
      dW, db, We, be, a, c, batch, groupOff,
      N, G, B1, B2, B4, B5);

  // deterministic CSR build (no global atomics)
  k_hist   <<<NSTRIPE, 256, 0, stream>>>(erow, hist, E, NB, shift, estripe);
  k_colscan<<<NB,      256, 0, stream>>>(hist, colTotal, NB);
  k_bscan  <<<1,       256, 0, stream>>>(colTotal, bucketBase, NB);
  k_scatter<<<NSTRIPE, 256, 0, stream>>>(erow, ecol, pos, hist, bucketBase,
                                         stg, E, NB, shift, estripe);
  k_place  <<<NB,      256, 0, stream>>>(stg, bucketBase, offsets, csr, N, NB, shift, E);

  int ntiles = (N + 15) >> 4;
  int segTiles = (((ntiles + NXCD - 1) / NXCD) + 1) & ~1;   // even tiles/XCD
  int segNodes = segTiles * 16;
  int segWJ = segTiles >> 1;
  int aggGrid  = NXCD * ((segNodes + 3) / 4);
  int gGrid    = NXCD * ((segWJ + 1) / 2);
  int nwj = (ntiles + 1) / 2;
  int pairGrid = (nwj + 1) / 2;
  k_gemm0<<<pairGrid, 128, 0, stream>>>(vhi, WnT, h0, N);

  for (int l = 0; l < NLAYER; ++l){
    size_t wo = (size_t)l * HDIM * HDIM;
    const ushortT* hin  = (l & 1) ? h1 : h0;
    ushortT*       hout = (l & 1) ? h0 : h1;
    k_agg2<<<aggGrid, 256, 0, stream>>>(hin, offsets, csr,
                                        a + l * HDIM, c + l * HDIM, agghi, N, segNodes);
    if (l < NLAYER - 1){
      size_t wn = (size_t)(l + 1) * HDIM * HDIM;
      k_fpair<<<gGrid, 128, 0, stream>>>(agghi, WoT + wo, bo + (size_t)l * HDIM,
                                         WnT + wn, hout, N, segTiles);
    } else {
      k_g1<<<gGrid, 128, 0, stream>>>(agghi, WoT + wo, bo + (size_t)l * HDIM,
                                      vb, N, segTiles);
      k_read<<<aggGrid, 256, 0, stream>>>(vb, W1, b1, W2, b2, u, N, segNodes);
    }
  }
  k_gsum<<<(G + 3) / 4, 256, 0, stream>>>(u, groupOff, (float*)d_out, G);
}

// Round 2
// 600.190 us; speedup vs baseline: 1.3183x; 1.0744x over previous
//
#include <hip/hip_runtime.h>
#include <math.h>

#define HDIM 128
#define NGAUSS 50
#define NLAYER 6
#define TSTR 136   // LDS bf16 tile row stride (shorts); %8==0 keeps ds_read_b128 aligned
#define DINV (1.0f/512.0f)
#define NXCD 8
#define NSTRIPE 512   // edge stripes for the deterministic CSR build

typedef unsigned short ushortT;
typedef __attribute__((ext_vector_type(8))) short bf16x8;
typedef __attribute__((ext_vector_type(4))) float f32x4;

static __device__ __forceinline__ float bf2f(unsigned short u){
  union { unsigned int i; float f; } x; x.i = ((unsigned int)u) << 16; return x.f;
}
static __device__ __forceinline__ unsigned short f2bf(float f){
  union { float f; unsigned int i; } x; x.f = f;
  unsigned int i = x.i;
  unsigned int r = (i + 0x7FFFu + ((i >> 16) & 1u)) >> 16;
  return (unsigned short)r;
}
static __device__ __forceinline__ float ssp(float x){
  return fmaxf(x, 0.0f) + __logf(1.0f + __expf(-fabsf(x))) - 0.69314718055994530942f;
}
static __device__ __forceinline__ f32x4 mfma4r(const bf16x8* a, const bf16x8* b){
  f32x4 d = {0.f, 0.f, 0.f, 0.f};
  d = __builtin_amdgcn_mfma_f32_16x16x32_bf16(a[0], b[0], d, 0, 0, 0);
  d = __builtin_amdgcn_mfma_f32_16x16x32_bf16(a[1], b[1], d, 0, 0, 0);
  d = __builtin_amdgcn_mfma_f32_16x16x32_bf16(a[2], b[2], d, 0, 0, 0);
  d = __builtin_amdgcn_mfma_f32_16x16x32_bf16(a[3], b[3], d, 0, 0, 0);
  return d;
}

// ======================= deterministic CSR build =======================
// stripe histograms -> column scans -> stripe-private contiguous scatter
// into row-bucket regions -> per-bucket regroup with LDS counters.

__global__ __launch_bounds__(256)
void k_hist(const int* __restrict__ erow, int* __restrict__ hist,
            int E, int NB, int shift, int estripe){
  __shared__ int lh[512];
  int tid = threadIdx.x, w = blockIdx.x;
  for (int i = tid; i < NB; i += 256) lh[i] = 0;
  __syncthreads();
  int beg = w * estripe;
  int end = beg + estripe; if (end > E) end = E;
  for (int e = beg + tid; e < end; e += 256)
    atomicAdd(&lh[erow[e] >> shift], 1);
  __syncthreads();
  for (int i = tid; i < NB; i += 256) hist[w * 512 + i] = lh[i];
}

__global__ __launch_bounds__(256)
void k_colscan(int* __restrict__ hist, int* __restrict__ colTotal, int NB){
  __shared__ int sA[512], sB[512];
  int b = blockIdx.x, tid = threadIdx.x;
  sA[tid]       = hist[tid * 512 + b];
  sA[tid + 256] = hist[(tid + 256) * 512 + b];
  __syncthreads();
  int* pa = sA; int* pb = sB;
  for (int off = 1; off < 512; off <<= 1){
    for (int i = tid; i < 512; i += 256)
      pb[i] = pa[i] + (i >= off ? pa[i - off] : 0);
    __syncthreads();
    int* t = pa; pa = pb; pb = t;
  }
  int e0 = (tid == 0) ? 0 : pa[tid - 1];
  int e1 = pa[tid + 255];
  hist[tid * 512 + b]       = e0;
  hist[(tid + 256) * 512 + b] = e1;
  if (tid == 0) colTotal[b] = pa[511];
}

__global__ __launch_bounds__(256)
void k_bscan(const int* __restrict__ colTotal, int* __restrict__ bucketBase, int NB){
  __shared__ int sA[512], sB[512];
  int tid = threadIdx.x;
  for (int i = tid; i < 512; i += 256) sA[i] = (i < NB) ? colTotal[i] : 0;
  __syncthreads();
  int* pa = sA; int* pb = sB;
  for (int off = 1; off < 512; off <<= 1){
    for (int i = tid; i < 512; i += 256)
      pb[i] = pa[i] + (i >= off ? pa[i - off] : 0);
    __syncthreads();
    int* t = pa; pa = pb; pb = t;
  }
  for (int i = tid; i < NB; i += 256)
    bucketBase[i] = (i == 0) ? 0 : pa[i - 1];
  if (tid == 0) bucketBase[NB] = pa[NB - 1];
}

__global__ __launch_bounds__(256)
void k_scatter(const int* __restrict__ erow, const int* __restrict__ ecol,
               const float* __restrict__ pos, const int* __restrict__ hist,
               const int* __restrict__ bucketBase, uint2* __restrict__ stg,
               int E, int NB, int shift, int estripe){
  __shared__ int cur[512];
  int tid = threadIdx.x, w = blockIdx.x;
  for (int b = tid; b < NB; b += 256)
    cur[b] = bucketBase[b] + hist[w * 512 + b];
  __syncthreads();
  int beg = w * estripe;
  int end = beg + estripe; if (end > E) end = E;
  int mask = (1 << shift) - 1;
  for (int e = beg + tid; e < end; e += 256){
    int r = erow[e], c = ecol[e];
    float dx = pos[r*3+0] - pos[c*3+0];
    float dy = pos[r*3+1] - pos[c*3+1];
    float dz = pos[r*3+2] - pos[c*3+2];
    float d = sqrtf(dx*dx + dy*dy + dz*dz);
    int du = (int)(d * 512.0f + 0.5f);
    if (du > 65535) du = 65535;
    int p = atomicAdd(&cur[r >> shift], 1);   // LDS atomic
    uint2 t;
    t.x = ((unsigned int)c << 16) | (unsigned int)du;
    t.y = (unsigned int)(r & mask);
    stg[p] = t;
  }
}

__global__ __launch_bounds__(256)
void k_place(const uint2* __restrict__ stg, const int* __restrict__ bucketBase,
             int* __restrict__ offsets, unsigned int* __restrict__ csr,
             int N, int NB, int shift, int E){
  __shared__ int rc[1024];
  __shared__ int sA[1024], sB[1024];
  int b = blockIdx.x, tid = threadIdx.x;
  int R = 1 << shift;
  int r0 = b << shift;
  int s = bucketBase[b], e2 = bucketBase[b + 1];
  for (int i = tid; i < R; i += 256) rc[i] = 0;
  __syncthreads();
  for (int j = s + tid; j < e2; j += 256)
    atomicAdd(&rc[stg[j].y], 1);
  __syncthreads();
  for (int i = tid; i < R; i += 256) sA[i] = rc[i];
  __syncthreads();
  int* pa = sA; int* pb = sB;
  for (int off = 1; off < R; off <<= 1){
    for (int i = tid; i < R; i += 256)
      pb[i] = pa[i] + (i >= off ? pa[i - off] : 0);
    __syncthreads();
    int* t = pa; pa = pb; pb = t;
  }
  for (int i = tid; i < R; i += 256){
    int excl = (i == 0) ? 0 : pa[i - 1];
    rc[i] = excl;
    int r = r0 + i;
    if (r < N) offsets[r] = s + excl;
  }
  if (b == NB - 1 && tid == 0) offsets[N] = E;
  __syncthreads();
  for (int j = s + tid; j < e2; j += 256){
    uint2 t = stg[j];
    int slot = s + atomicAdd(&rc[t.y], 1);   // LDS atomic
    csr[slot] = t.x;
  }
}

// ---------------- merged setup ----------------
__global__ void k_setup(const int* __restrict__ z, const float* __restrict__ emb,
                        ushortT* __restrict__ vhi,
                        const float* __restrict__ Wn, ushortT* __restrict__ WnT,
                        const float* __restrict__ Wo, ushortT* __restrict__ WoT,
                        const float* __restrict__ dW, const float* __restrict__ db,
                        const float* __restrict__ We, const float* __restrict__ be,
                        float* __restrict__ a, float* __restrict__ c,
                        const int* __restrict__ batch, int* __restrict__ groupOff,
                        const float* __restrict__ W1, ushortT* __restrict__ W1T,
                        int N, int G, int B1, int B2, int B4, int B5, int B7){
  int b = blockIdx.x;
  int tid = threadIdx.x;
  if (b < B1){
    int idx = b * 256 + tid;
    if (idx < N * HDIM){
      int n = idx >> 7, f = idx & 127;
      vhi[idx] = f2bf(emb[z[n] * HDIM + f]);
    }
    return;
  }
  b -= B1;
  if (b < B2){
    int idx = b * 256 + tid;
    if (idx < NLAYER * HDIM * HDIM){
      int mat = idx >> 14, rem = idx & 16383;
      int n = rem >> 7, k = rem & 127;
      WnT[idx] = f2bf(Wn[(mat << 14) + k * HDIM + n]);
    }
    return;
  }
  b -= B2;
  if (b < B2){
    int idx = b * 256 + tid;
    if (idx < NLAYER * HDIM * HDIM){
      int mat = idx >> 14, rem = idx & 16383;
      int n = rem >> 7, k = rem & 127;
      WoT[idx] = f2bf(Wo[(mat << 14) + k * HDIM + n]);
    }
    return;
  }
  b -= B2;
  if (b < B4){
    int idx = b * 256 + tid;
    if (idx < NLAYER * HDIM){
      int l = idx >> 7, f = idx & 127;
      float av = 0.f, cv = 0.f;
      for (int g = 0; g < NGAUSS; ++g){
        float we = We[(l * NGAUSS + g) * HDIM + f];
        av += dW[g] * we;
        cv += db[g] * we;
      }
      a[idx] = av;
      c[idx] = cv + be[idx];
    }
    return;
  }
  b -= B4;
  if (b < B5){
    int i = b * 256 + tid;
    if (i >= N) return;
    int bb = batch[i];
    if (i == 0){
      for (int g = 0; g <= bb; ++g) groupOff[g] = 0;
    } else {
      int pb = batch[i - 1];
      for (int g = pb + 1; g <= bb; ++g) groupOff[g] = i;
    }
    if (i == N - 1){
      for (int g = bb + 1; g <= G; ++g) groupOff[g] = N;
    }
    return;
  }
  b -= B5;
  if (b < B7){
    int idx = b * 256 + tid;
    if (idx < 64 * HDIM){
      int ncol = idx >> 7, k = idx & 127;
      W1T[idx] = f2bf(W1[k * 64 + ncol]);
    }
  }
}

// ---------------- initial GEMM: h0 = v0 @ Wn[0]; 2 row-tiles per wave ----------
__global__ __launch_bounds__(128, 2)
void k_gemm0(const ushortT* __restrict__ X, const ushortT* __restrict__ WT,
             ushortT* __restrict__ outHi, int N){
  int tid = threadIdx.x;
  int wave = tid >> 6, lane = tid & 63;
  int m = lane & 15, quad = lane >> 4;
  int ntiles = (N + 15) >> 4;
  int t0 = (blockIdx.x * 2 + wave) * 2;
  if (t0 >= ntiles) return;

  bf16x8 av[2][4];
  #pragma unroll
  for (int rt = 0; rt < 2; ++rt){
    int row = (t0 + rt) * 16 + m; if (row >= N) row = N - 1;
    #pragma unroll
    for (int kk = 0; kk < 4; ++kk)
      av[rt][kk] = *(const bf16x8*)(X + ((size_t)row << 7) + kk*32 + quad*8);
  }
  #pragma unroll
  for (int ct = 0; ct < 8; ++ct){
    int ncol = ct * 16 + m;
    const ushortT* bp = WT + ((size_t)ncol << 7) + quad*8;
    bf16x8 bb[4];
    #pragma unroll
    for (int kk = 0; kk < 4; ++kk) bb[kk] = *(const bf16x8*)(bp + kk*32);
    #pragma unroll
    for (int rt = 0; rt < 2; ++rt){
      f32x4 d = mfma4r(av[rt], bb);
      #pragma unroll
      for (int r = 0; r < 4; ++r){
        int orow = (t0 + rt) * 16 + quad*4 + r;
        if (orow < N) outHi[((size_t)orow << 7) + ncol] = f2bf(d[r]);
      }
    }
  }
}

// ---------------- edge aggregation, XCD-swizzled node ownership ----------------
__global__ __launch_bounds__(256, 8)
void k_agg2(const ushortT* __restrict__ h, const int* __restrict__ offsets,
            const unsigned int* __restrict__ cd, const float* __restrict__ a,
            const float* __restrict__ c, ushortT* __restrict__ aggHi,
            int N, int segNodes){
  int xcd = blockIdx.x & (NXCD - 1);
  int idx = blockIdx.x >> 3;
  int node = xcd * segNodes + idx * 4 + (threadIdx.x >> 6);
  if (node >= N || node >= (xcd + 1) * segNodes) return;
  int lane = threadIdx.x & 63;
  int half = lane >> 5;
  int fl = (lane & 31) * 4;
  float4 av = *(const float4*)(a + fl);
  float4 cv = *(const float4*)(c + fl);
  int s = offsets[node], e = offsets[node + 1];
  float acc0 = 0.f, acc1 = 0.f, acc2 = 0.f, acc3 = 0.f;
  int j = s;
  for (; j + 8 <= e; j += 8){
    unsigned int q[4]; uint2 p[4];
    #pragma unroll
    for (int i = 0; i < 4; ++i) q[i] = cd[j + 2*i + half];
    #pragma unroll
    for (int i = 0; i < 4; ++i)
      p[i] = *(const uint2*)(h + ((size_t)(q[i] >> 16) << 7) + fl);
    #pragma unroll
    for (int i = 0; i < 4; ++i){
      float dd = (float)(q[i] & 0xFFFFu) * DINV;
      acc0 = fmaf(bf2f((ushortT)p[i].x),         fmaf(dd, av.x, cv.x), acc0);
      acc1 = fmaf(bf2f((ushortT)(p[i].x >> 16)), fmaf(dd, av.y, cv.y), acc1);
      acc2 = fmaf(bf2f((ushortT)p[i].y),         fmaf(dd, av.z, cv.z), acc2);
      acc3 = fmaf(bf2f((ushortT)(p[i].y >> 16)), fmaf(dd, av.w, cv.w), acc3);
    }
  }
  for (; j < e; j += 2){
    int myj = j + half;
    if (myj < e){
      unsigned int q = cd[myj];
      uint2 p = *(const uint2*)(h + ((size_t)(q >> 16) << 7) + fl);
      float dd = (float)(q & 0xFFFFu) * DINV;
      acc0 = fmaf(bf2f((ushortT)p.x),         fmaf(dd, av.x, cv.x), acc0);
      acc1 = fmaf(bf2f((ushortT)(p.x >> 16)), fmaf(dd, av.y, cv.y), acc1);
      acc2 = fmaf(bf2f((ushortT)p.y),         fmaf(dd, av.z, cv.z), acc2);
      acc3 = fmaf(bf2f((ushortT)(p.y >> 16)), fmaf(dd, av.w, cv.w), acc3);
    }
  }
  acc0 += __shfl_down(acc0, 32, 64);
  acc1 += __shfl_down(acc1, 32, 64);
  acc2 += __shfl_down(acc2, 32, 64);
  acc3 += __shfl_down(acc3, 32, 64);
  if (half == 0){
    uint2 ph;
    ph.x = (unsigned int)f2bf(acc0) | ((unsigned int)f2bf(acc1) << 16);
    ph.y = (unsigned int)f2bf(acc2) | ((unsigned int)f2bf(acc3) << 16);
    *(uint2*)(aggHi + ((size_t)node << 7) + fl) = ph;
  }
}

// ---------------- fused GEMM pair, wave-private LDS, no barrier ----------------
__global__ __launch_bounds__(128, 2)
void k_fpair(const ushortT* __restrict__ agg, const ushortT* __restrict__ WoT,
             const float* __restrict__ bo, const ushortT* __restrict__ WnT,
             ushortT* __restrict__ outH, int N, int segTiles){
  __shared__ ushortT vt[2][32 * TSTR];
  int tid = threadIdx.x;
  int wave = tid >> 6, lane = tid & 63;
  int m = lane & 15, quad = lane >> 4;
  int ntiles = (N + 15) >> 4;
  int xcd = blockIdx.x & (NXCD - 1);
  int idx = blockIdx.x >> 3;
  int wjIdx = idx * 2 + wave;
  int segWJ = segTiles >> 1;
  if (wjIdx >= segWJ) return;
  int t0 = xcd * segTiles + wjIdx * 2;
  if (t0 >= ntiles) return;
  ushortT* vw = vt[wave];

  bf16x8 av[2][4];
  #pragma unroll
  for (int rt = 0; rt < 2; ++rt){
    int row = (t0 + rt) * 16 + m; if (row >= N) row = N - 1;
    #pragma unroll
    for (int kk = 0; kk < 4; ++kk)
      av[rt][kk] = *(const bf16x8*)(agg + ((size_t)row << 7) + kk*32 + quad*8);
  }
  #pragma unroll
  for (int ct = 0; ct < 8; ++ct){
    int ncol = ct * 16 + m;
    const ushortT* bp = WoT + ((size_t)ncol << 7) + quad*8;
    bf16x8 bb[4];
    #pragma unroll
    for (int kk = 0; kk < 4; ++kk) bb[kk] = *(const bf16x8*)(bp + kk*32);
    float bbias = bo[ncol];
    #pragma unroll
    for (int rt = 0; rt < 2; ++rt){
      f32x4 d = mfma4r(av[rt], bb);
      #pragma unroll
      for (int r = 0; r < 4; ++r)
        vw[(rt*16 + quad*4 + r) * TSTR + ncol] = f2bf(ssp(d[r] + bbias));
    }
  }
  bf16x8 a2[2][4];
  #pragma unroll
  for (int rt = 0; rt < 2; ++rt){
    #pragma unroll
    for (int kk = 0; kk < 4; ++kk)
      a2[rt][kk] = *(const bf16x8*)(&vw[(rt*16 + m) * TSTR + kk*32 + quad*8]);
  }
  #pragma unroll
  for (int ct = 0; ct < 8; ++ct){
    int ncol = ct * 16 + m;
    const ushortT* bp = WnT + ((size_t)ncol << 7) + quad*8;
    bf16x8 bb[4];
    #pragma unroll
    for (int kk = 0; kk < 4; ++kk) bb[kk] = *(const bf16x8*)(bp + kk*32);
    #pragma unroll
    for (int rt = 0; rt < 2; ++rt){
      f32x4 d = mfma4r(a2[rt], bb);
      #pragma unroll
      for (int r = 0; r < 4; ++r){
        int orow = (t0 + rt) * 16 + quad*4 + r;
        if (orow < N) outH[((size_t)orow << 7) + ncol] = f2bf(d[r]);
      }
    }
  }
}

// ------ last layer fused: v=ssp(agg@Wo+bo); u = ssp(v@W1+b1)@W2 + b2 ----------
// Same wave-private-LDS transpose trick as k_fpair; GEMM2 is 64 cols (4 ct)
// against W1T, epilogue folds W2 and a 16-lane quad-reduce writes u directly.
// Replaces k_g1 + k_read (one wave per node, latency-bound FMA chain, 55us).
__global__ __launch_bounds__(128, 2)
void k_gfinal(const ushortT* __restrict__ agg, const ushortT* __restrict__ WoT,
              const float* __restrict__ bo, const ushortT* __restrict__ W1T,
              const float* __restrict__ b1, const float* __restrict__ W2,
              const float* __restrict__ b2, float* __restrict__ u,
              int N, int segTiles){
  __shared__ ushortT vt[2][32 * TSTR];
  int tid = threadIdx.x;
  int wave = tid >> 6, lane = tid & 63;
  int m = lane & 15, quad = lane >> 4;
  int ntiles = (N + 15) >> 4;
  int xcd = blockIdx.x & (NXCD - 1);
  int idx = blockIdx.x >> 3;
  int wjIdx = idx * 2 + wave;
  int segWJ = segTiles >> 1;
  if (wjIdx >= segWJ) return;
  int t0 = xcd * segTiles + wjIdx * 2;
  if (t0 >= ntiles) return;
  ushortT* vw = vt[wave];

  // GEMM1: v = ssp(agg @ Wo + bo) -> wave-private LDS
  bf16x8 av[2][4];
  #pragma unroll
  for (int rt = 0; rt < 2; ++rt){
    int row = (t0 + rt) * 16 + m; if (row >= N) row = N - 1;
    #pragma unroll
    for (int kk = 0; kk < 4; ++kk)
      av[rt][kk] = *(const bf16x8*)(agg + ((size_t)row << 7) + kk*32 + quad*8);
  }
  #pragma unroll
  for (int ct = 0; ct < 8; ++ct){
    int ncol = ct * 16 + m;
    const ushortT* bp = WoT + ((size_t)ncol << 7) + quad*8;
    bf16x8 bb[4];
    #pragma unroll
    for (int kk = 0; kk < 4; ++kk) bb[kk] = *(const bf16x8*)(bp + kk*32);
    float bbias = bo[ncol];
    #pragma unroll
    for (int rt = 0; rt < 2; ++rt){
      f32x4 d = mfma4r(av[rt], bb);
      #pragma unroll
      for (int r = 0; r < 4; ++r)
        vw[(rt*16 + quad*4 + r) * TSTR + ncol] = f2bf(ssp(d[r] + bbias));
    }
  }
  // GEMM2: [32 rows] x W1T[64,128]; epilogue ssp(+b1)*W2 and quad-reduce
  bf16x8 a2[2][4];
  #pragma unroll
  for (int rt = 0; rt < 2; ++rt){
    #pragma unroll
    for (int kk = 0; kk < 4; ++kk)
      a2[rt][kk] = *(const bf16x8*)(&vw[(rt*16 + m) * TSTR + kk*32 + quad*8]);
  }
  float acc[2][4] = {{0.f,0.f,0.f,0.f},{0.f,0.f,0.f,0.f}};
  #pragma unroll
  for (int ct = 0; ct < 4; ++ct){
    int ncol = ct * 16 + m;
    const ushortT* bp = W1T + ((size_t)ncol << 7) + quad*8;
    bf16x8 bb[4];
    #pragma unroll
    for (int kk = 0; kk < 4; ++kk) bb[kk] = *(const bf16x8*)(bp + kk*32);
    float bb1 = b1[ncol];
    float w2  = W2[ncol];
    #pragma unroll
    for (int rt = 0; rt < 2; ++rt){
      f32x4 d = mfma4r(a2[rt], bb);
      #pragma unroll
      for (int r = 0; r < 4; ++r)
        acc[rt][r] += ssp(d[r] + bb1) * w2;
    }
  }
  float bb2 = b2[0];
  #pragma unroll
  for (int rt = 0; rt < 2; ++rt){
    #pragma unroll
    for (int r = 0; r < 4; ++r){
      float v = acc[rt][r];
      v += __shfl_xor(v, 1, 64);
      v += __shfl_xor(v, 2, 64);
      v += __shfl_xor(v, 4, 64);
      v += __shfl_xor(v, 8, 64);
      if (m == 0){
        int orow = (t0 + rt) * 16 + quad*4 + r;
        if (orow < N) u[orow] = v + bb2;
      }
    }
  }
}

// ---------------- group segment sum over sorted batch ----------------
__global__ void k_gsum(const float* __restrict__ u, const int* __restrict__ groupOff,
                       float* __restrict__ out, int G){
  int g = blockIdx.x * 4 + (threadIdx.x >> 6);
  if (g >= G) return;
  int lane = threadIdx.x & 63;
  int s = groupOff[g], e = groupOff[g + 1];
  float acc = 0.f;
  for (int j = s + lane; j < e; j += 64) acc += u[j];
  #pragma unroll
  for (int off = 32; off > 0; off >>= 1)
    acc += __shfl_down(acc, off, 64);
  if (lane == 0) out[g] = acc;
}

extern "C" void kernel_launch(void* const* d_in, const int* in_sizes, int n_in,
                              void* d_out, int out_size, void* d_ws, size_t ws_size,
                              hipStream_t stream){
  const int N = in_sizes[0];
  const int E = in_sizes[3] / 2;
  const int G = out_size;

  const int*   z     = (const int*)d_in[0];
  const float* pos   = (const float*)d_in[1];
  const int*   batch = (const int*)d_in[2];
  const int*   eidx  = (const int*)d_in[3];
  const int*   erow  = eidx;
  const int*   ecol  = eidx + E;
  const float* emb   = (const float*)d_in[4];
  const float* dW    = (const float*)d_in[5];
  const float* db    = (const float*)d_in[6];
  const float* Wn    = (const float*)d_in[7];
  const float* We    = (const float*)d_in[8];
  const float* be    = (const float*)d_in[9];
  const float* Wo    = (const float*)d_in[10];
  const float* bo    = (const float*)d_in[11];
  const float* W1    = (const float*)d_in[12];
  const float* b1    = (const float*)d_in[13];
  const float* W2    = (const float*)d_in[14];
  const float* b2    = (const float*)d_in[15];

  char* ws = (char*)d_ws;
  size_t off = 0;
  auto alloc = [&](size_t bytes) -> char* {
    char* p = ws + off;
    off = (off + bytes + 255) & ~(size_t)255;
    return p;
  };
  size_t hbytes = (size_t)N * HDIM * 2;
  size_t stgbytes = (size_t)E * 8;
  int*          offsets  = (int*)         alloc((size_t)(N + 1) * 4);
  unsigned int* csr      = (unsigned int*)alloc((size_t)E * 4);
  ushortT*      h0       = (ushortT*)     alloc(hbytes);
  ushortT*      h1       = (ushortT*)     alloc(hbytes);    // aliased by hist during build
  ushortT*      vhi      = (ushortT*)     alloc(hbytes);
  ushortT*      agghi    = (ushortT*)     alloc(hbytes);
  ushortT*      stgbuf   = (ushortT*)     alloc(stgbytes);  // CSR staging records
  ushortT*      WnT      = (ushortT*)     alloc((size_t)NLAYER * HDIM * HDIM * 2);
  ushortT*      WoT      = (ushortT*)     alloc((size_t)NLAYER * HDIM * HDIM * 2);
  ushortT*      W1T      = (ushortT*)     alloc((size_t)64 * HDIM * 2);
  float*        a        = (float*)       alloc((size_t)NLAYER * HDIM * 4);
  float*        c        = (float*)       alloc((size_t)NLAYER * HDIM * 4);
  float*        u        = (float*)       alloc((size_t)N * 4);
  int*          groupOff = (int*)         alloc((size_t)(G + 1) * 4);

  // CSR-build scratch aliases h1 (first written by layer-0 k_fpair).
  int*   hist       = (int*)h1;                 // NSTRIPE*512 ints = 1 MB
  int*   colTotal   = hist + NSTRIPE * 512;     // 512 ints
  int*   bucketBase = colTotal + 512;           // NB+1 ints
  uint2* stg        = (uint2*)stgbuf;           // E * 8 B

  int shift = 7;
  while ((((N - 1) >> shift) + 1) > 512) ++shift;
  int NB = ((N - 1) >> shift) + 1;
  int estripe = (E + NSTRIPE - 1) / NSTRIPE;

  int B1 = (N * HDIM + 255) / 256;
  int B2 = (NLAYER * HDIM * HDIM + 255) / 256;
  int B4 = (NLAYER * HDIM + 255) / 256;
  int B5 = (N + 255) / 256;
  int B7 = (64 * HDIM + 255) / 256;
  k_setup<<<B1 + 2*B2 + B4 + B5 + B7, 256, 0, stream>>>(
      z, emb, vhi, Wn, WnT, Wo, WoT,
      dW, db, We, be, a, c, batch, groupOff, W1, W1T,
      N, G, B1, B2, B4, B5, B7);

  // deterministic CSR build (no global atomics)
  k_hist   <<<NSTRIPE, 256, 0, stream>>>(erow, hist, E, NB, shift, estripe);
  k_colscan<<<NB,      256, 0, stream>>>(hist, colTotal, NB);
  k_bscan  <<<1,       256, 0, stream>>>(colTotal, bucketBase, NB);
  k_scatter<<<NSTRIPE, 256, 0, stream>>>(erow, ecol, pos, hist, bucketBase,
                                         stg, E, NB, shift, estripe);
  k_place  <<<NB,      256, 0, stream>>>(stg, bucketBase, offsets, csr, N, NB, shift, E);

  int ntiles = (N + 15) >> 4;
  int segTiles = (((ntiles + NXCD - 1) / NXCD) + 1) & ~1;   // even tiles/XCD
  int segNodes = segTiles * 16;
  int segWJ = segTiles >> 1;
  int aggGrid  = NXCD * ((segNodes + 3) / 4);
  int gGrid    = NXCD * ((segWJ + 1) / 2);
  int nwj = (ntiles + 1) / 2;
  int pairGrid = (nwj + 1) / 2;
  k_gemm0<<<pairGrid, 128, 0, stream>>>(vhi, WnT, h0, N);

  for (int l = 0; l < NLAYER; ++l){
    size_t wo = (size_t)l * HDIM * HDIM;
    const ushortT* hin  = (l & 1) ? h1 : h0;
    ushortT*       hout = (l & 1) ? h0 : h1;
    k_agg2<<<aggGrid, 256, 0, stream>>>(hin, offsets, csr,
                                        a + l * HDIM, c + l * HDIM, agghi, N, segNodes);
    if (l < NLAYER - 1){
      size_t wn = (size_t)(l + 1) * HDIM * HDIM;
      k_fpair<<<gGrid, 128, 0, stream>>>(agghi, WoT + wo, bo + (size_t)l * HDIM,
                                         WnT + wn, hout, N, segTiles);
    } else {
      k_gfinal<<<gGrid, 128, 0, stream>>>(agghi, WoT + wo, bo + (size_t)l * HDIM,
                                          W1T, b1, W2, b2, u, N, segTiles);
    }
  }
  k_gsum<<<(G + 3) / 4, 256, 0, stream>>>(u, groupOff, (float*)d_out, G);
}